// Round 1
// baseline (775.131 us; speedup 1.0000x reference)
//
#include <hip/hip_runtime.h>
#include <math.h>

// TbpNet: B=16, A=256, NBH=64, F=128, K=25, L=3. fp32 baseline (Round 0).
#define NB   16
#define NA   256
#define NNBH 64
#define NF   128
#define NK   25
#define NATOM (NB*NA)   // 4096

__device__ __constant__ float BINOM_C[25] = {
  1.f, 24.f, 276.f, 2024.f, 10626.f, 42504.f, 134596.f, 346104.f,
  735471.f, 1307504.f, 1961256.f, 2496144.f, 2704156.f, 2496144.f,
  1961256.f, 1307504.f, 735471.f, 346104.f, 134596.f, 42504.f,
  10626.f, 2024.f, 276.f, 24.f, 1.f
};

__device__ __forceinline__ float sspf(float x) {
  float t = (x > 20.f) ? x : log1pf(expf(x));
  return t - 0.69314718055994531f;
}

// ---------------- embedding ----------------
__global__ void k_embed(const int* __restrict__ Z, const float* __restrict__ emb,
                        float* __restrict__ x) {
  int i = blockIdx.x * 256 + threadIdx.x;           // grid exactly covers 4096*128
  x[i] = emb[Z[i >> 7] * NF + (i & 127)];
}

// ---------------- generic 128x128 GEMM over 4096 rows ----------------
// Out[r][c] = act( (maskin? X*amask : X) @ W + bias )
template<int ACT, int MASKIN>
__device__ __forceinline__ void gemm_body(float* XT, float* Wl,
    const float* __restrict__ X, const float* __restrict__ W,
    const float* __restrict__ bias, const float* __restrict__ amask,
    float* __restrict__ Out) {
  int tid = threadIdx.x;
  int rbase = blockIdx.x * 64;
  // stage X^T : XT[kk][r], 64 rows x 128 k, pad stride 68
  #pragma unroll
  for (int j = 0; j < 32; j++) {
    int e = j * 256 + tid;
    int r = e >> 7, kk = e & 127;
    float v = X[(rbase + r) * NF + kk];
    if (MASKIN) v *= amask[rbase + r];
    XT[kk * 68 + r] = v;
  }
  int tr = tid >> 5;   // 0..7 -> rows tr*8..+7
  int tc = tid & 31;   // cols tc*4..+3
  float acc[8][4];
  #pragma unroll
  for (int i = 0; i < 8; i++)
    #pragma unroll
    for (int j = 0; j < 4; j++) acc[i][j] = 0.f;

  for (int kc = 0; kc < 4; kc++) {
    __syncthreads();
    #pragma unroll
    for (int j = 0; j < 16; j++) {
      int e = j * 256 + tid;
      int kk = e >> 7, c = e & 127;
      Wl[kk * 132 + c] = W[(kc * 32 + kk) * NF + c];
    }
    __syncthreads();
    #pragma unroll 8
    for (int kk = 0; kk < 32; kk++) {
      const float* xrow = &XT[(kc * 32 + kk) * 68 + tr * 8];
      float4 a0 = *(const float4*)xrow;
      float4 a1 = *(const float4*)(xrow + 4);
      float4 b  = *(const float4*)&Wl[kk * 132 + tc * 4];
      float av[8] = {a0.x, a0.y, a0.z, a0.w, a1.x, a1.y, a1.z, a1.w};
      #pragma unroll
      for (int i = 0; i < 8; i++) {
        acc[i][0] += av[i] * b.x;  acc[i][1] += av[i] * b.y;
        acc[i][2] += av[i] * b.z;  acc[i][3] += av[i] * b.w;
      }
    }
  }
  float bv[4] = {0.f, 0.f, 0.f, 0.f};
  if (bias) {
    float4 b4 = *(const float4*)&bias[tc * 4];
    bv[0] = b4.x; bv[1] = b4.y; bv[2] = b4.z; bv[3] = b4.w;
  }
  #pragma unroll
  for (int i = 0; i < 8; i++) {
    int row = rbase + tr * 8 + i;
    float o[4];
    #pragma unroll
    for (int j = 0; j < 4; j++) {
      o[j] = acc[i][j] + bv[j];
      if (ACT) o[j] = sspf(o[j]);
    }
    float4 o4 = make_float4(o[0], o[1], o[2], o[3]);
    *(float4*)&Out[row * NF + tc * 4] = o4;
  }
}

template<int ACT, int MASKIN>
__global__ __launch_bounds__(256) void k_gemm_plain(const float* __restrict__ X,
    const float* __restrict__ W, const float* __restrict__ bias,
    const float* __restrict__ amask, float* __restrict__ Out) {
  __shared__ float XT[128 * 68];
  __shared__ float Wl[32 * 132];
  gemm_body<ACT, MASKIN>(XT, Wl, X, W, bias, amask, Out);
}

__global__ __launch_bounds__(256) void k_gemm_qkv(const float* __restrict__ X,
    const float* __restrict__ W0, const float* __restrict__ W1,
    const float* __restrict__ W2, const float* __restrict__ amask,
    float* __restrict__ O0, float* __restrict__ O1, float* __restrict__ O2) {
  __shared__ float XT[128 * 68];
  __shared__ float Wl[32 * 132];
  int z = blockIdx.z;
  const float* W = (z == 0) ? W0 : ((z == 1) ? W1 : W2);
  float* O = (z == 0) ? O0 : ((z == 1) ? O1 : O2);
  gemm_body<1, 1>(XT, Wl, X, W, nullptr, amask, O);
}

// ---------------- filter / local interaction (one block per atom) ----------------
// c[f] = cs[f] + cp[f], cs = sum_n yj*( (f*fc)@Wfs ), cp = sum_m (sum_n dhat_m*yj*((f*fc)@Wfp))^2
__global__ __launch_bounds__(128) void k_filter(const float* __restrict__ y,
    const int* __restrict__ nbrs, const float* __restrict__ pos,
    const float* __restrict__ nmask, const float* __restrict__ Wfs,
    const float* __restrict__ Wfp, float* __restrict__ cOut) {
  __shared__ float ffl[64 * 28];   // basis*fc, n-major, pad 28 (25 valid + 3 zero)
  __shared__ float dhl[64 * 4];    // dhat, pad 4
  __shared__ int   jl[64];
  __shared__ float yjl[64 * 128];  // gathered y rows
  int tid = threadIdx.x;
  int atom = blockIdx.x;
  int brow = atom & ~(NA - 1);     // batch row base (A=256 power of 2)

  // per-thread weight columns (f = tid)
  float wfs[28], wfp[28];
  #pragma unroll
  for (int k = 0; k < NK; k++) {
    wfs[k] = Wfs[k * NF + tid];
    wfp[k] = Wfp[k * NF + tid];
  }
  wfs[25] = wfs[26] = wfs[27] = 0.f;
  wfp[25] = wfp[26] = wfp[27] = 0.f;

  if (tid < NNBH) {
    int n = tid;
    int j = nbrs[atom * NNBH + n];
    jl[n] = j;
    float px = pos[(brow + j) * 3 + 0] - pos[atom * 3 + 0];
    float py = pos[(brow + j) * 3 + 1] - pos[atom * 3 + 1];
    float pz = pos[(brow + j) * 3 + 2] - pos[atom * 3 + 2];
    float m = nmask[atom * NNBH + n];
    float r = sqrtf(px * px + py * py + pz * pz + 1e-12f) * m;
    float inv = 1.0f / (r + 1e-9f);
    dhl[n * 4 + 0] = px * inv;
    dhl[n * 4 + 1] = py * inv;
    dhl[n * 4 + 2] = pz * inv;
    dhl[n * 4 + 3] = 0.f;
    float fcv = (r < 5.0f) ? (0.5f * cosf(0.62831853071795865f * r) + 0.5f) * m : 0.0f;
    float xe = expf(-r);
    float p1 = xe + 1e-10f;
    float p2 = 1.0f - xe + 1e-10f;
    float pk[25];
    float aa = 1.0f;
    #pragma unroll
    for (int k = 0; k < NK; k++) { pk[k] = BINOM_C[k] * aa; aa *= p1; }
    float bw = fcv;                  // fold cutoff*mask into basis
    #pragma unroll
    for (int k = NK - 1; k >= 0; k--) { ffl[n * 28 + k] = pk[k] * bw; bw *= p2; }
    ffl[n * 28 + 25] = 0.f; ffl[n * 28 + 26] = 0.f; ffl[n * 28 + 27] = 0.f;
  }
  __syncthreads();

  // gather neighbor y rows
  #pragma unroll 4
  for (int n = 0; n < NNBH; n++) {
    yjl[n * 128 + tid] = y[(brow + jl[n]) * NF + tid];
  }
  __syncthreads();

  float cs = 0.f, t0 = 0.f, t1 = 0.f, t2 = 0.f;
  #pragma unroll 2
  for (int n = 0; n < NNBH; n++) {
    float yj = yjl[n * 128 + tid];
    const float4* fp = (const float4*)(ffl + n * 28);
    float ws = 0.f, wp = 0.f;
    #pragma unroll
    for (int q = 0; q < 7; q++) {
      float4 f4 = fp[q];
      ws += f4.x * wfs[4*q+0];  wp += f4.x * wfp[4*q+0];
      ws += f4.y * wfs[4*q+1];  wp += f4.y * wfp[4*q+1];
      ws += f4.z * wfs[4*q+2];  wp += f4.z * wfp[4*q+2];
      ws += f4.w * wfs[4*q+3];  wp += f4.w * wfp[4*q+3];
    }
    cs += yj * ws;
    float ywp = yj * wp;
    float4 d4 = *(const float4*)(dhl + n * 4);
    t0 += d4.x * ywp;  t1 += d4.y * ywp;  t2 += d4.z * ywp;
  }
  cOut[atom * NF + tid] = cs + t0 * t0 + t1 * t1 + t2 * t2;
}

// ---------------- fused attention + residual (one block per 16 q-rows) ----------------
__global__ __launch_bounds__(256) void k_attn(const float* __restrict__ q,
    const float* __restrict__ kmat, const float* __restrict__ vv,
    const float* __restrict__ amask, const float* __restrict__ vres,
    float* __restrict__ x) {
  __shared__ float ql[16 * 132];
  __shared__ float kl[128 * 68];   // reused as vvl[32*132] in PV phase
  __shared__ float attl[16 * 260];
  int tid = threadIdx.x;
  int bidx = blockIdx.x;
  int b = bidx >> 4;
  int r0 = (bidx & 15) * 16;
  int growbase = b * NA + r0;

  #pragma unroll
  for (int j = 0; j < 8; j++) {
    int e = j * 256 + tid;
    int r = e >> 7, kk = e & 127;
    ql[r * 132 + kk] = q[(growbase + r) * NF + kk];
  }

  int r  = tid >> 4;   // 0..15 (row)
  int cg = tid & 15;   // col group
  const float scale = 0.08838834764831845f;  // 1/sqrt(128)

  // logits: 4 chunks of 64 columns
  for (int cc = 0; cc < 4; cc++) {
    __syncthreads();
    #pragma unroll
    for (int j = 0; j < 32; j++) {
      int e = j * 256 + tid;
      int c = e >> 7, kk = e & 127;
      kl[kk * 68 + c] = kmat[(b * NA + cc * 64 + c) * NF + kk];
    }
    __syncthreads();
    float acc[4] = {0.f, 0.f, 0.f, 0.f};
    #pragma unroll 4
    for (int k4 = 0; k4 < 32; k4++) {
      float4 qv = *(const float4*)&ql[r * 132 + k4 * 4];
      #pragma unroll
      for (int t = 0; t < 4; t++) {
        float4 kv = *(const float4*)&kl[(k4 * 4 + t) * 68 + cg * 4];
        float qc = (t == 0) ? qv.x : (t == 1) ? qv.y : (t == 2) ? qv.z : qv.w;
        acc[0] += qc * kv.x;  acc[1] += qc * kv.y;
        acc[2] += qc * kv.z;  acc[3] += qc * kv.w;
      }
    }
    #pragma unroll
    for (int j = 0; j < 4; j++)
      attl[r * 260 + cc * 64 + cg * 4 + j] = acc[j] * scale;
  }
  __syncthreads();

  // masked softmax over 256 cols; 16 lanes per row
  float lv[16];
  float mx = -1e30f;
  #pragma unroll
  for (int i = 0; i < 16; i++) {
    int c = cg + 16 * i;
    float lg = attl[r * 260 + c] + (1.0f - amask[b * NA + c]) * (-1e9f);
    lv[i] = lg;
    mx = fmaxf(mx, lg);
  }
  #pragma unroll
  for (int s = 1; s < 16; s <<= 1) mx = fmaxf(mx, __shfl_xor(mx, s, 16));
  float sum = 0.f;
  #pragma unroll
  for (int i = 0; i < 16; i++) { float e = expf(lv[i] - mx); lv[i] = e; sum += e; }
  #pragma unroll
  for (int s = 1; s < 16; s <<= 1) sum += __shfl_xor(sum, s, 16);
  float isum = 1.0f / sum;
  #pragma unroll
  for (int i = 0; i < 16; i++) attl[r * 260 + cg + 16 * i] = lv[i] * isum;

  // PV: out[r][f0..f0+7] = sum_c att[r][c]*vv[c][f]
  float* vvl = kl;                 // alias (4224 <= 8704 floats)
  int f0 = (tid & 15) * 8;
  float po[8] = {0.f,0.f,0.f,0.f,0.f,0.f,0.f,0.f};
  for (int cc = 0; cc < 8; cc++) {
    __syncthreads();               // protects attl writes (cc=0) and prev vvl reads
    #pragma unroll
    for (int j = 0; j < 16; j++) {
      int e = j * 256 + tid;
      int c = e >> 7, f = e & 127;
      vvl[c * 132 + f] = vv[(b * NA + cc * 32 + c) * NF + f];
    }
    __syncthreads();
    #pragma unroll 4
    for (int c = 0; c < 32; c++) {
      float av = attl[r * 260 + cc * 32 + c];
      float4 v0 = *(const float4*)&vvl[c * 132 + f0];
      float4 v1 = *(const float4*)&vvl[c * 132 + f0 + 4];
      po[0] += av * v0.x;  po[1] += av * v0.y;
      po[2] += av * v0.z;  po[3] += av * v0.w;
      po[4] += av * v1.x;  po[5] += av * v1.y;
      po[6] += av * v1.z;  po[7] += av * v1.w;
    }
  }
  // residual update: x = x + v + n*atom_mask
  int grow = growbase + r;
  float am = amask[grow];
  float4 x0 = *(float4*)&x[grow * NF + f0];
  float4 x1 = *(float4*)&x[grow * NF + f0 + 4];
  const float4 v0 = *(const float4*)&vres[grow * NF + f0];
  const float4 v1 = *(const float4*)&vres[grow * NF + f0 + 4];
  x0.x += v0.x + po[0] * am;  x0.y += v0.y + po[1] * am;
  x0.z += v0.z + po[2] * am;  x0.w += v0.w + po[3] * am;
  x1.x += v1.x + po[4] * am;  x1.y += v1.y + po[5] * am;
  x1.z += v1.z + po[6] * am;  x1.w += v1.w + po[7] * am;
  *(float4*)&x[grow * NF + f0]     = x0;
  *(float4*)&x[grow * NF + f0 + 4] = x1;
}

// ---------------- host launch ----------------
extern "C" void kernel_launch(void* const* d_in, const int* in_sizes, int n_in,
                              void* d_out, int out_size, void* d_ws, size_t ws_size,
                              hipStream_t stream) {
  const float* pos   = (const float*)d_in[0];
  const float* nmask = (const float*)d_in[1];
  const float* amask = (const float*)d_in[2];
  const float* emb   = (const float*)d_in[3];
  const float* Wfs   = (const float*)d_in[4];
  const float* Wfp   = (const float*)d_in[5];
  const float* Win   = (const float*)d_in[6];
  const float* Wf2o  = (const float*)d_in[7];
  const float* bf2o  = (const float*)d_in[8];
  const float* Wd    = (const float*)d_in[9];
  const float* bd    = (const float*)d_in[10];
  const float* Wq    = (const float*)d_in[11];
  const float* Wk    = (const float*)d_in[12];
  const float* Wv    = (const float*)d_in[13];
  const int*   Z     = (const int*)d_in[14];
  const int*   nbrs  = (const int*)d_in[15];

  float* x = (float*)d_out;
  float* wsf = (float*)d_ws;
  const int S = NATOM * NF;                 // 524288
  float* Yb  = wsf;            // y, then reused as h
  float* Cb  = wsf + S;
  float* Vb  = wsf + 2 * S;
  float* Qb  = wsf + 3 * S;
  float* Kb  = wsf + 4 * S;
  float* VVb = wsf + 5 * S;

  k_embed<<<dim3(NATOM * NF / 256), dim3(256), 0, stream>>>(Z, emb, x);

  for (int l = 0; l < 3; l++) {
    const float* Wfs_l  = Wfs  + l * NK * NF;
    const float* Wfp_l  = Wfp  + l * NK * NF;
    const float* Win_l  = Win  + l * NF * NF;
    const float* Wf2o_l = Wf2o + l * NF * NF;
    const float* bf2o_l = bf2o + l * NF;
    const float* Wd_l   = Wd   + l * NF * NF;
    const float* bd_l   = bd   + l * NF;
    const float* Wq_l   = Wq   + l * NF * NF;
    const float* Wk_l   = Wk   + l * NF * NF;
    const float* Wv_l   = Wv   + l * NF * NF;

    // y = x @ Win
    k_gemm_plain<0, 0><<<dim3(64), dim3(256), 0, stream>>>(x, Win_l, nullptr, nullptr, Yb);
    // c = cs + cp
    k_filter<<<dim3(NATOM), dim3(128), 0, stream>>>(Yb, nbrs, pos, nmask, Wfs_l, Wfp_l, Cb);
    // h = ssp(c @ Wf2o + bf2o)   (reuse Yb)
    k_gemm_plain<1, 0><<<dim3(64), dim3(256), 0, stream>>>(Cb, Wf2o_l, bf2o_l, nullptr, Yb);
    // v = h @ Wd + bd
    k_gemm_plain<0, 0><<<dim3(64), dim3(256), 0, stream>>>(Yb, Wd_l, bd_l, nullptr, Vb);
    // q,k,vv = ssp((x*amask) @ W{q,k,v})
    k_gemm_qkv<<<dim3(64, 1, 3), dim3(256), 0, stream>>>(x, Wq_l, Wk_l, Wv_l, amask, Qb, Kb, VVb);
    // attention + residual: x = x + v + n
    k_attn<<<dim3(NB * (NA / 16)), dim3(256), 0, stream>>>(Qb, Kb, VVb, amask, Vb, x);
  }
}

// Round 2
// 439.529 us; speedup vs baseline: 1.7636x; 1.7636x over previous
//
#include <hip/hip_runtime.h>
#include <hip/hip_bf16.h>
#include <math.h>

// TbpNet: B=16, A=256, NBH=64, F=128, K=25, L=3.
// R1: filter -> per-atom MFMA GEMM over neighbor axis (bf16 in, fp32 acc).
#define NB   16
#define NA   256
#define NNBH 64
#define NF   128
#define NK   25
#define NATOM (NB*NA)   // 4096

typedef __attribute__((ext_vector_type(4))) float f32x4;
typedef __attribute__((ext_vector_type(8))) short bf16x8;

__device__ __constant__ float BINOM_C[25] = {
  1.f, 24.f, 276.f, 2024.f, 10626.f, 42504.f, 134596.f, 346104.f,
  735471.f, 1307504.f, 1961256.f, 2496144.f, 2704156.f, 2496144.f,
  1961256.f, 1307504.f, 735471.f, 346104.f, 134596.f, 42504.f,
  10626.f, 2024.f, 276.f, 24.f, 1.f
};

__device__ __forceinline__ float sspf(float x) {
  float t = (x > 20.f) ? x : log1pf(expf(x));
  return t - 0.69314718055994531f;
}

__device__ __forceinline__ unsigned short f2bf(float x) {
  __hip_bfloat16 h = __float2bfloat16(x);
  return *(unsigned short*)&h;
}

// ---------------- embedding ----------------
__global__ void k_embed(const int* __restrict__ Z, const float* __restrict__ emb,
                        float* __restrict__ x) {
  int i = blockIdx.x * 256 + threadIdx.x;
  x[i] = emb[Z[i >> 7] * NF + (i & 127)];
}

// ---------------- extended weight table [L][2 bands][32][128] ----------------
// band0 rows 0..24 = Wfs, band1 rows 0..24 = Wfp, rows 25..31 = 0
__global__ void k_wext(const float* __restrict__ Wfs, const float* __restrict__ Wfp,
                       float* __restrict__ Wext) {
  int idx = blockIdx.x * 256 + threadIdx.x;     // 3*2*32*128 = 24576
  int f    = idx & 127;
  int kk   = (idx >> 7) & 31;
  int band = (idx >> 12) & 1;
  int l    = idx >> 13;
  float v = 0.f;
  if (kk < NK) v = (band ? Wfp : Wfs)[l * NK * NF + kk * NF + f];
  Wext[idx] = v;
}

// ---------------- generic 128x128 GEMM over 4096 rows ----------------
template<int ACT, int MASKIN, int OBF16>
__device__ __forceinline__ void gemm_body(float* XT, float* Wl,
    const float* __restrict__ X, const float* __restrict__ W,
    const float* __restrict__ bias, const float* __restrict__ amask,
    void* __restrict__ Out) {
  int tid = threadIdx.x;
  int rbase = blockIdx.x * 64;
  #pragma unroll
  for (int j = 0; j < 32; j++) {
    int e = j * 256 + tid;
    int r = e >> 7, kk = e & 127;
    float v = X[(rbase + r) * NF + kk];
    if (MASKIN) v *= amask[rbase + r];
    XT[kk * 68 + r] = v;
  }
  int tr = tid >> 5;
  int tc = tid & 31;
  float acc[8][4];
  #pragma unroll
  for (int i = 0; i < 8; i++)
    #pragma unroll
    for (int j = 0; j < 4; j++) acc[i][j] = 0.f;

  for (int kc = 0; kc < 4; kc++) {
    __syncthreads();
    #pragma unroll
    for (int j = 0; j < 16; j++) {
      int e = j * 256 + tid;
      int kk = e >> 7, c = e & 127;
      Wl[kk * 132 + c] = W[(kc * 32 + kk) * NF + c];
    }
    __syncthreads();
    #pragma unroll 8
    for (int kk = 0; kk < 32; kk++) {
      const float* xrow = &XT[(kc * 32 + kk) * 68 + tr * 8];
      float4 a0 = *(const float4*)xrow;
      float4 a1 = *(const float4*)(xrow + 4);
      float4 b  = *(const float4*)&Wl[kk * 132 + tc * 4];
      float av[8] = {a0.x, a0.y, a0.z, a0.w, a1.x, a1.y, a1.z, a1.w};
      #pragma unroll
      for (int i = 0; i < 8; i++) {
        acc[i][0] += av[i] * b.x;  acc[i][1] += av[i] * b.y;
        acc[i][2] += av[i] * b.z;  acc[i][3] += av[i] * b.w;
      }
    }
  }
  float bv[4] = {0.f, 0.f, 0.f, 0.f};
  if (bias) {
    float4 b4 = *(const float4*)&bias[tc * 4];
    bv[0] = b4.x; bv[1] = b4.y; bv[2] = b4.z; bv[3] = b4.w;
  }
  #pragma unroll
  for (int i = 0; i < 8; i++) {
    int row = rbase + tr * 8 + i;
    float o[4];
    #pragma unroll
    for (int j = 0; j < 4; j++) {
      o[j] = acc[i][j] + bv[j];
      if (ACT) o[j] = sspf(o[j]);
    }
    if (OBF16) {
      uint2 u;
      u.x = (unsigned)f2bf(o[0]) | ((unsigned)f2bf(o[1]) << 16);
      u.y = (unsigned)f2bf(o[2]) | ((unsigned)f2bf(o[3]) << 16);
      *(uint2*)((__hip_bfloat16*)Out + row * NF + tc * 4) = u;
    } else {
      float4 o4 = make_float4(o[0], o[1], o[2], o[3]);
      *(float4*)((float*)Out + row * NF + tc * 4) = o4;
    }
  }
}

template<int ACT, int MASKIN, int OBF16>
__global__ __launch_bounds__(256) void k_gemm_plain(const float* __restrict__ X,
    const float* __restrict__ W, const float* __restrict__ bias,
    const float* __restrict__ amask, void* __restrict__ Out) {
  __shared__ float XT[128 * 68];
  __shared__ float Wl[32 * 132];
  gemm_body<ACT, MASKIN, OBF16>(XT, Wl, X, W, bias, amask, Out);
}

__global__ __launch_bounds__(256) void k_gemm_qkv(const float* __restrict__ X,
    const float* __restrict__ W0, const float* __restrict__ W1,
    const float* __restrict__ W2, const float* __restrict__ amask,
    float* __restrict__ O0, float* __restrict__ O1, float* __restrict__ O2) {
  __shared__ float XT[128 * 68];
  __shared__ float Wl[32 * 132];
  int z = blockIdx.z;
  const float* W = (z == 0) ? W0 : ((z == 1) ? W1 : W2);
  float* O = (z == 0) ? O0 : ((z == 1) ? O1 : O2);
  gemm_body<1, 1, 0>(XT, Wl, X, W, nullptr, amask, O);
}

// ---------------- MFMA filter: per-atom G = FFE @ YJ, fused epilogue ----------------
// FFE[k'][n]: k' in 4 bands of 32 (rows 25..31 of each band zero):
//   band0: basis*fc, band1..3: basis*fc*dhat_{x,y,z}
// G[k'][f] = sum_n FFE[k'][n] * y[nbr(n)][f]  (MFMA 16x16x32 bf16)
// c[f] = sum_k Wfs[k][f]*G[b0] + sum_m (sum_k Wfp[k][f]*G[b1+m])^2
__global__ __launch_bounds__(256) void k_filter_mfma(
    const __hip_bfloat16* __restrict__ ybf, const int* __restrict__ nbrs,
    const float* __restrict__ pos, const float* __restrict__ nmask,
    const float* __restrict__ Wext, float* __restrict__ cOut) {
  __shared__ __hip_bfloat16 FFE[128 * 72];   // 18432 B, row stride 72 (144 B)
  __shared__ __hip_bfloat16 YJT[128 * 72];   // YJT[f][n]
  __shared__ int jl[NNBH];
  int tid = threadIdx.x;
  int atom = blockIdx.x;
  int brow = atom & ~(NA - 1);

  // zero the band pad rows (kk 25..31 of each band), cols 0..71
  for (int i = tid; i < 28 * 36; i += 256) {
    int r = i / 36;                 // 0..27
    int band = r / 7, kk = 25 + (r - band * 7);
    int col = i - (r * 36);
    ((unsigned*)FFE)[(band * 32 + kk) * 36 + col] = 0u;
  }

  // geometry + Bernstein walk (one thread per neighbor)
  if (tid < NNBH) {
    int n = tid;
    int j = nbrs[atom * NNBH + n];
    jl[n] = j;
    float px = pos[(brow + j) * 3 + 0] - pos[atom * 3 + 0];
    float py = pos[(brow + j) * 3 + 1] - pos[atom * 3 + 1];
    float pz = pos[(brow + j) * 3 + 2] - pos[atom * 3 + 2];
    float m = nmask[atom * NNBH + n];
    float r = sqrtf(px * px + py * py + pz * pz + 1e-12f) * m;
    float inv = 1.0f / (r + 1e-9f);
    float dx = px * inv, dy = py * inv, dz = pz * inv;
    float fcv = (r < 5.0f) ? (0.5f * cosf(0.62831853071795865f * r) + 0.5f) * m : 0.0f;
    float xe = expf(-r);
    float p1 = xe + 1e-10f;
    float p2 = 1.0f - xe + 1e-10f;
    float pk[25];
    float aa = 1.0f;
    #pragma unroll
    for (int k = 0; k < NK; k++) { pk[k] = BINOM_C[k] * aa; aa *= p1; }
    float bw = fcv;
    #pragma unroll
    for (int k = NK - 1; k >= 0; k--) {
      float ff = pk[k] * bw; bw *= p2;
      FFE[(     k) * 72 + n] = __float2bfloat16(ff);
      FFE[(32 + k) * 72 + n] = __float2bfloat16(ff * dx);
      FFE[(64 + k) * 72 + n] = __float2bfloat16(ff * dy);
      FFE[(96 + k) * 72 + n] = __float2bfloat16(ff * dz);
    }
  }
  __syncthreads();

  // gather y rows (bf16) transposed: YJT[f][n]
  {
    int f = tid & 127, q = tid >> 7;
    #pragma unroll
    for (int p = 0; p < 16; p++) {
      int n0 = (p * 2 + q) * 2;
      unsigned a = *(const unsigned short*)&ybf[(brow + jl[n0    ]) * NF + f];
      unsigned b = *(const unsigned short*)&ybf[(brow + jl[n0 + 1]) * NF + f];
      *(unsigned*)((char*)YJT + f * 144 + n0 * 2) = a | (b << 16);
    }
  }
  __syncthreads();

  int lane = tid & 63, w = tid >> 6;
  int lr = lane & 15, lg = lane >> 4;

  f32x4 acc[8][2];
  #pragma unroll
  for (int mt = 0; mt < 8; mt++)
    #pragma unroll
    for (int nt = 0; nt < 2; nt++) acc[mt][nt] = (f32x4){0.f, 0.f, 0.f, 0.f};

  #pragma unroll
  for (int s = 0; s < 2; s++) {
    bf16x8 b0 = *(bf16x8*)((char*)YJT + (32 * w      + lr) * 144 + lg * 16 + s * 64);
    bf16x8 b1 = *(bf16x8*)((char*)YJT + (32 * w + 16 + lr) * 144 + lg * 16 + s * 64);
    #pragma unroll
    for (int mt = 0; mt < 8; mt++) {
      bf16x8 af = *(bf16x8*)((char*)FFE + (16 * mt + lr) * 144 + lg * 16 + s * 64);
      acc[mt][0] = __builtin_amdgcn_mfma_f32_16x16x32_bf16(af, b0, acc[mt][0], 0, 0, 0);
      acc[mt][1] = __builtin_amdgcn_mfma_f32_16x16x32_bf16(af, b1, acc[mt][1], 0, 0, 0);
    }
  }

  // epilogue: weighted k-reduction per f + cross-lane (k' spread over lane>>4)
  #pragma unroll
  for (int nt = 0; nt < 2; nt++) {
    int f = 32 * w + 16 * nt + lr;
    float ps = 0.f, pp0 = 0.f, pp1 = 0.f, pp2 = 0.f;
    #pragma unroll
    for (int mt = 0; mt < 8; mt++) {
      const float* wrow = Wext + ((mt >> 1) ? (32 * NF) : 0) + (16 * (mt & 1) + 4 * lg) * NF + f;
      #pragma unroll
      for (int jj = 0; jj < 4; jj++) {
        float t = wrow[jj * NF] * acc[mt][nt][jj];
        if      ((mt >> 1) == 0) ps  += t;
        else if ((mt >> 1) == 1) pp0 += t;
        else if ((mt >> 1) == 2) pp1 += t;
        else                     pp2 += t;
      }
    }
    ps  += __shfl_xor(ps, 16);  ps  += __shfl_xor(ps, 32);
    pp0 += __shfl_xor(pp0, 16); pp0 += __shfl_xor(pp0, 32);
    pp1 += __shfl_xor(pp1, 16); pp1 += __shfl_xor(pp1, 32);
    pp2 += __shfl_xor(pp2, 16); pp2 += __shfl_xor(pp2, 32);
    if (lg == 0)
      cOut[atom * NF + f] = ps + pp0 * pp0 + pp1 * pp1 + pp2 * pp2;
  }
}

// ---------------- fused attention + residual ----------------
__global__ __launch_bounds__(256) void k_attn(const float* __restrict__ q,
    const float* __restrict__ kmat, const float* __restrict__ vv,
    const float* __restrict__ amask, const float* __restrict__ vres,
    float* __restrict__ x) {
  __shared__ float ql[16 * 132];
  __shared__ float kl[128 * 68];
  __shared__ float attl[16 * 260];
  int tid = threadIdx.x;
  int bidx = blockIdx.x;
  int b = bidx >> 4;
  int r0 = (bidx & 15) * 16;
  int growbase = b * NA + r0;

  #pragma unroll
  for (int j = 0; j < 8; j++) {
    int e = j * 256 + tid;
    int r = e >> 7, kk = e & 127;
    ql[r * 132 + kk] = q[(growbase + r) * NF + kk];
  }

  int r  = tid >> 4;
  int cg = tid & 15;
  const float scale = 0.08838834764831845f;

  for (int cc = 0; cc < 4; cc++) {
    __syncthreads();
    #pragma unroll
    for (int j = 0; j < 32; j++) {
      int e = j * 256 + tid;
      int c = e >> 7, kk = e & 127;
      kl[kk * 68 + c] = kmat[(b * NA + cc * 64 + c) * NF + kk];
    }
    __syncthreads();
    float acc[4] = {0.f, 0.f, 0.f, 0.f};
    #pragma unroll 4
    for (int k4 = 0; k4 < 32; k4++) {
      float4 qv = *(const float4*)&ql[r * 132 + k4 * 4];
      #pragma unroll
      for (int t = 0; t < 4; t++) {
        float4 kv = *(const float4*)&kl[(k4 * 4 + t) * 68 + cg * 4];
        float qc = (t == 0) ? qv.x : (t == 1) ? qv.y : (t == 2) ? qv.z : qv.w;
        acc[0] += qc * kv.x;  acc[1] += qc * kv.y;
        acc[2] += qc * kv.z;  acc[3] += qc * kv.w;
      }
    }
    #pragma unroll
    for (int j = 0; j < 4; j++)
      attl[r * 260 + cc * 64 + cg * 4 + j] = acc[j] * scale;
  }
  __syncthreads();

  float lv[16];
  float mx = -1e30f;
  #pragma unroll
  for (int i = 0; i < 16; i++) {
    int c = cg + 16 * i;
    float lg = attl[r * 260 + c] + (1.0f - amask[b * NA + c]) * (-1e9f);
    lv[i] = lg;
    mx = fmaxf(mx, lg);
  }
  #pragma unroll
  for (int s = 1; s < 16; s <<= 1) mx = fmaxf(mx, __shfl_xor(mx, s, 16));
  float sum = 0.f;
  #pragma unroll
  for (int i = 0; i < 16; i++) { float e = expf(lv[i] - mx); lv[i] = e; sum += e; }
  #pragma unroll
  for (int s = 1; s < 16; s <<= 1) sum += __shfl_xor(sum, s, 16);
  float isum = 1.0f / sum;
  #pragma unroll
  for (int i = 0; i < 16; i++) attl[r * 260 + cg + 16 * i] = lv[i] * isum;

  float* vvl = kl;
  int f0 = (tid & 15) * 8;
  float po[8] = {0.f,0.f,0.f,0.f,0.f,0.f,0.f,0.f};
  for (int cc = 0; cc < 8; cc++) {
    __syncthreads();
    #pragma unroll
    for (int j = 0; j < 16; j++) {
      int e = j * 256 + tid;
      int c = e >> 7, f = e & 127;
      vvl[c * 132 + f] = vv[(b * NA + cc * 32 + c) * NF + f];
    }
    __syncthreads();
    #pragma unroll 4
    for (int c = 0; c < 32; c++) {
      float av = attl[r * 260 + cc * 32 + c];
      float4 v0 = *(const float4*)&vvl[c * 132 + f0];
      float4 v1 = *(const float4*)&vvl[c * 132 + f0 + 4];
      po[0] += av * v0.x;  po[1] += av * v0.y;
      po[2] += av * v0.z;  po[3] += av * v0.w;
      po[4] += av * v1.x;  po[5] += av * v1.y;
      po[6] += av * v1.z;  po[7] += av * v1.w;
    }
  }
  int grow = growbase + r;
  float am = amask[grow];
  float4 x0 = *(float4*)&x[grow * NF + f0];
  float4 x1 = *(float4*)&x[grow * NF + f0 + 4];
  const float4 v0 = *(const float4*)&vres[grow * NF + f0];
  const float4 v1 = *(const float4*)&vres[grow * NF + f0 + 4];
  x0.x += v0.x + po[0] * am;  x0.y += v0.y + po[1] * am;
  x0.z += v0.z + po[2] * am;  x0.w += v0.w + po[3] * am;
  x1.x += v1.x + po[4] * am;  x1.y += v1.y + po[5] * am;
  x1.z += v1.z + po[6] * am;  x1.w += v1.w + po[7] * am;
  *(float4*)&x[grow * NF + f0]     = x0;
  *(float4*)&x[grow * NF + f0 + 4] = x1;
}

// ---------------- host launch ----------------
extern "C" void kernel_launch(void* const* d_in, const int* in_sizes, int n_in,
                              void* d_out, int out_size, void* d_ws, size_t ws_size,
                              hipStream_t stream) {
  const float* pos   = (const float*)d_in[0];
  const float* nmask = (const float*)d_in[1];
  const float* amask = (const float*)d_in[2];
  const float* emb   = (const float*)d_in[3];
  const float* Wfs   = (const float*)d_in[4];
  const float* Wfp   = (const float*)d_in[5];
  const float* Win   = (const float*)d_in[6];
  const float* Wf2o  = (const float*)d_in[7];
  const float* bf2o  = (const float*)d_in[8];
  const float* Wd    = (const float*)d_in[9];
  const float* bd    = (const float*)d_in[10];
  const float* Wq    = (const float*)d_in[11];
  const float* Wk    = (const float*)d_in[12];
  const float* Wv    = (const float*)d_in[13];
  const int*   Z     = (const int*)d_in[14];
  const int*   nbrs  = (const int*)d_in[15];

  float* x = (float*)d_out;
  float* wsf = (float*)d_ws;
  const int S = NATOM * NF;                 // 524288
  float* Hb  = wsf;                         // h (and pre-filter c reuse chain)
  float* Cb  = wsf + S;
  float* Vb  = wsf + 2 * S;
  float* Qb  = wsf + 3 * S;
  float* Kb  = wsf + 4 * S;
  float* VVb = wsf + 5 * S;
  __hip_bfloat16* ybf = (__hip_bfloat16*)(wsf + 6 * S);   // S bf16 = S/2 floats
  float* Wext = wsf + 6 * S + S / 2;                      // 3*2*32*128 floats

  k_wext<<<dim3(96), dim3(256), 0, stream>>>(Wfs, Wfp, Wext);
  k_embed<<<dim3(NATOM * NF / 256), dim3(256), 0, stream>>>(Z, emb, x);

  for (int l = 0; l < 3; l++) {
    const float* Win_l  = Win  + l * NF * NF;
    const float* Wf2o_l = Wf2o + l * NF * NF;
    const float* bf2o_l = bf2o + l * NF;
    const float* Wd_l   = Wd   + l * NF * NF;
    const float* bd_l   = bd   + l * NF;
    const float* Wq_l   = Wq   + l * NF * NF;
    const float* Wk_l   = Wk   + l * NF * NF;
    const float* Wv_l   = Wv   + l * NF * NF;
    const float* Wext_l = Wext + l * 2 * 32 * NF;

    // y = x @ Win  -> bf16
    k_gemm_plain<0, 0, 1><<<dim3(64), dim3(256), 0, stream>>>(x, Win_l, nullptr, nullptr, ybf);
    // c = cs + cp via per-atom MFMA
    k_filter_mfma<<<dim3(NATOM), dim3(256), 0, stream>>>(ybf, nbrs, pos, nmask, Wext_l, Cb);
    // h = ssp(c @ Wf2o + bf2o)
    k_gemm_plain<1, 0, 0><<<dim3(64), dim3(256), 0, stream>>>(Cb, Wf2o_l, bf2o_l, nullptr, Hb);
    // v = h @ Wd + bd
    k_gemm_plain<0, 0, 0><<<dim3(64), dim3(256), 0, stream>>>(Hb, Wd_l, bd_l, nullptr, Vb);
    // q,k,vv = ssp((x*amask) @ W{q,k,v})
    k_gemm_qkv<<<dim3(64, 1, 3), dim3(256), 0, stream>>>(x, Wq_l, Wk_l, Wv_l, amask, Qb, Kb, VVb);
    // attention + residual
    k_attn<<<dim3(NB * (NA / 16)), dim3(256), 0, stream>>>(Qb, Kb, VVb, amask, Vb, x);
  }
}